// Round 2
// baseline (217.330 us; speedup 1.0000x reference)
//
#include <hip/hip_runtime.h>
#include <hip/hip_bf16.h>

// MultiHeadSelfAttention: B=2 S=2048 D=1024 H=16 DK=64. fp32 I/O, bf16 internals.
// [cvt x+W fused] -> [QKV gemm (Q pre-scaled by 0.125*log2e, V transposed)] ->
// [flash attn v3: swapped QK^T (mfma(K,Q), 32x32x16), in-register softmax via
//  v_exp_f32 + cvt_pk_bf16 + permlane32_swap; KEY-SPLIT 8-wave blocks (group 0:
//  tiles 0-15, group 1: tiles 16-31; exact combine o=oA+oB,l=lA+lB via LDS);
//  double-buffered K/V per group; XCD-bijective swizzle] -> [out-proj].
// ws (bf16 elems): xb/ctx[0], Q[4M], K[8M], Vt[12M], Wb[16M..20M] => 40 MB.

#define DEV __device__ __forceinline__

typedef __bf16 bf16_t;
typedef __bf16 bf16x4 __attribute__((ext_vector_type(4)));
typedef __bf16 bf16x8 __attribute__((ext_vector_type(8)));
typedef float f32x4 __attribute__((ext_vector_type(4)));
typedef float f32x16 __attribute__((ext_vector_type(16)));
typedef unsigned int u32;

constexpr int Ss = 2048, Dd = 1024, Hh = 16, DKk = 64;

DEV void gload_lds16(const void* g, void* l) {
  __builtin_amdgcn_global_load_lds(
      (__attribute__((address_space(1))) void*)(g),
      (__attribute__((address_space(3))) void*)(l), 16, 0, 0);
}

DEV bf16_t f2b(float v) { return (bf16_t)v; }

DEV u32 cvtpk(float lo, float hi) {
  u32 r;
  asm("v_cvt_pk_bf16_f32 %0, %1, %2" : "=v"(r) : "v"(lo), "v"(hi));
  return r;
}

// new a0[l+32] = old b0[l]; new b0[l] = old a0[l+32] (lanes l<32).
DEV void swap32(u32& a, u32& b) {
  asm("v_permlane32_swap_b32 %0, %1" : "+v"(a), "+v"(b));
}

DEV float exp2_fast(float x) {  // 2^x, single v_exp_f32
  float r;
  asm("v_exp_f32 %0, %1" : "=v"(r) : "v"(x));
  return r;
}

// 16 fp32 -> bf16 (32B out)
DEV void cvt16_core(const float* src, bf16_t* dst) {
  const float4* s4 = (const float4*)src;
  float4 a = s4[0], b = s4[1], c = s4[2], d = s4[3];
  bf16x8 lo = {f2b(a.x), f2b(a.y), f2b(a.z), f2b(a.w), f2b(b.x), f2b(b.y), f2b(b.z), f2b(b.w)};
  bf16x8 hi = {f2b(c.x), f2b(c.y), f2b(c.z), f2b(c.w), f2b(d.x), f2b(d.y), f2b(d.z), f2b(d.w)};
  *(bf16x8*)dst = lo;
  *(bf16x8*)(dst + 8) = hi;
}

__global__ __launch_bounds__(256) void cvt16(const float* __restrict__ x,
                                             bf16_t* __restrict__ xb) {
  size_t i = ((size_t)blockIdx.x * 256 + threadIdx.x) * 16;
  cvt16_core(x + i, xb + i);
}

// fused: x (4M) -> xb; Wq/Wk/Wv/Wo (1M each) -> Wb. grid 2048x256.
__global__ __launch_bounds__(256) void cvt_all(
    const float* __restrict__ x,
    const float* __restrict__ wq, const float* __restrict__ wk,
    const float* __restrict__ wv, const float* __restrict__ wo,
    bf16_t* __restrict__ xb, bf16_t* __restrict__ Wb) {
  size_t i = ((size_t)blockIdx.x * 256 + threadIdx.x) * 16;
  const size_t XN = (size_t)4 << 20;
  if (i < XN) {
    cvt16_core(x + i, xb + i);
  } else {
    size_t j = i - XN;
    int z = (int)(j >> 20);
    size_t o = j & (((size_t)1 << 20) - 1);
    const float* s = (z == 0) ? wq : ((z == 1) ? wk : ((z == 2) ? wv : wo));
    cvt16_core(s + o, Wb + j);
  }
}

// ---------------------------------------------------------------------------
// QKV GEMM: C = xb @ W^T + b. z=0 Q [B*H,S,DK] (pre-scaled by 0.125*log2e);
// z=1 K [B*H,S,DK]; z=2 Vt [B*H,DK,S] (packed 8B stores).
// XCD-bijective block swizzle over 768 = 8 x 96 workgroups.
// ---------------------------------------------------------------------------
template <bool WB16>
__global__ __launch_bounds__(256) void gemm_qkv(
    const bf16_t* __restrict__ A,
    const float* __restrict__ W0, const float* __restrict__ W1, const float* __restrict__ W2,
    const bf16_t* __restrict__ Wb,
    const float* __restrict__ b0, const float* __restrict__ b1, const float* __restrict__ b2,
    bf16_t* __restrict__ o0, bf16_t* __restrict__ o1, bf16_t* __restrict__ o2) {
  // swizzle: fid -> xcd-contiguous chunks (768 % 8 == 0, bijective)
  const int fid = (int)((blockIdx.z * gridDim.y + blockIdx.y) * gridDim.x + blockIdx.x);
  const int swz = (fid & 7) * 96 + (fid >> 3);
  const int bx = swz & 7, by = (swz >> 3) & 31, z = swz >> 8;

  const float* Wf = (z == 0) ? W0 : ((z == 1) ? W1 : W2);
  const bf16_t* Wbf = Wb + (size_t)z * (1u << 20);
  const float* bias = (z == 0) ? b0 : ((z == 1) ? b1 : b2);
  bf16_t* out = (z == 0) ? o0 : ((z == 1) ? o1 : o2);
  const float scl = (z == 0) ? 0.18033688f : 1.0f;  // 0.125 * log2(e)

  __shared__ __align__(16) bf16_t As[128 * 32];
  __shared__ __align__(16) bf16_t Ws[128 * 32];

  const int tid = threadIdx.x;
  const int lane = tid & 63, w = tid >> 6;
  const int quad = lane >> 4, c = lane & 15;
  const int wm = w >> 1, wn = w & 1;
  const int m0 = by * 128, n0 = bx * 128;
  const int trow = tid >> 1, tcol = (tid & 1) * 16;
  const int srow = lane >> 2, scol = (lane & 3) * 8;

  const f32x4 vzero = {0.f, 0.f, 0.f, 0.f};
  f32x4 acc[4][4];
  for (int i = 0; i < 4; i++)
    for (int j = 0; j < 4; j++) acc[i][j] = vzero;

  for (int k0 = 0; k0 < 1024; k0 += 32) {
    for (int r = 0; r < 2; r++) {
      int row = r * 64 + w * 16;  // wave-uniform LDS base
      gload_lds16(&A[(size_t)(m0 + row + srow) * 1024 + k0 + scol], &As[row * 32]);
      if (WB16)
        gload_lds16(&Wbf[(size_t)(n0 + row + srow) * 1024 + k0 + scol], &Ws[row * 32]);
    }
    if (!WB16)
      cvt16_core(&Wf[(size_t)(n0 + trow) * 1024 + k0 + tcol], &Ws[trow * 32 + tcol]);
    __syncthreads();

    bf16x8 af[4], bfr[4];
    for (int i = 0; i < 4; i++)
      af[i] = *(const bf16x8*)&As[(wm * 64 + i * 16 + c) * 32 + quad * 8];
    for (int j = 0; j < 4; j++)
      bfr[j] = *(const bf16x8*)&Ws[(wn * 64 + j * 16 + c) * 32 + quad * 8];
    for (int i = 0; i < 4; i++)
      for (int j = 0; j < 4; j++)
        acc[i][j] = __builtin_amdgcn_mfma_f32_16x16x32_bf16(af[i], bfr[j], acc[i][j], 0, 0, 0);
    __syncthreads();
  }

  for (int j = 0; j < 4; j++) {
    int n = n0 + wn * 64 + j * 16 + c;
    float bv = bias[n];
    for (int i = 0; i < 4; i++) {
      int mbase = m0 + wm * 64 + i * 16 + quad * 4;
      int b_ = mbase >> 11, s_ = mbase & 2047;
      int h_ = n >> 6, dk_ = n & 63;
      if (z < 2) {
        for (int r = 0; r < 4; r++)
          out[((size_t)(b_ * Hh + h_) * Ss + (s_ + r)) * DKk + dk_] =
              f2b((acc[i][j][r] + bv) * scl);
      } else {
        bf16x4 pk;
        for (int r = 0; r < 4; r++) pk[r] = f2b(acc[i][j][r] + bv);
        *(bf16x4*)&out[((size_t)(b_ * Hh + h_) * DKk + dk_) * Ss + s_] = pk;
      }
    }
  }
}

// ---------------------------------------------------------------------------
// Flash attention v3: swapped QK^T, in-register softmax, KEY-SPLIT 8 waves.
// Grid 512 blocks x 512 threads. Waves 0-3 (group 0): key tiles 0..15;
// waves 4-7 (group 1): tiles 16..31. Each group double-buffers its own
// 64x64 K/V LDS tiles. Exact combine (no online max): o=oA+oB, l=lA+lB
// via 48KB LDS scratch (reuses staging buffers after last barrier).
// mfma_f32_32x32x16_bf16: A[m=lane&31][k=(lane>>5)*8+j]; C col=lane&31,
// row=(reg&3)+8*(reg>>2)+4*(lane>>5).
// ---------------------------------------------------------------------------
__global__ __launch_bounds__(512, 4) void attn_fwd(
    const bf16_t* __restrict__ Q, const bf16_t* __restrict__ K,
    const bf16_t* __restrict__ Vt, const int* __restrict__ mask,
    bf16_t* __restrict__ ctx) {
  __shared__ __align__(16) bf16_t smem[2][2][2][64 * 64];  // [K/V][grp][buf] 64KB

  const int tid = threadIdx.x, lane = tid & 63, w = tid >> 6;
  const int g = w >> 2, wl = w & 3;
  const int m = lane & 31, hi = lane >> 5;

  // XCD-bijective swizzle: 512 wgs = 8 xcds x 64; each XCD owns 4 whole heads.
  const int fid = (int)(blockIdx.y * gridDim.x + blockIdx.x);
  const int xcd = fid & 7, j_ = fid >> 3;
  const int bh = xcd * 4 + (j_ >> 4);
  const int qblk = j_ & 15;

  const int b_ = bh >> 4, h_ = bh & 15;
  const int q0 = qblk * 128 + wl * 32;
  const size_t head = (size_t)bh * Ss * DKk;
  const int* maskb = mask + b_ * Ss + g * 1024;
  const int kbase = g * 16;  // this group's first key tile

  bf16_t (*Ksg)[64 * 64] = smem[0][g];
  bf16_t (*Vtg)[64 * 64] = smem[1][g];

  const int sr = lane >> 3;        // staging row within 8
  const int gc = (lane & 7) ^ sr;  // swizzled source chunk

  // prefetch this group's tile 0 into buf 0
  for (int r = 0; r < 2; r++) {
    int row = r * 32 + wl * 8;  // wave-uniform
    gload_lds16(&K[head + (size_t)(kbase * 64 + row + sr) * 64 + gc * 8], &Ksg[0][row * 64]);
    gload_lds16(&Vt[head + (size_t)(row + sr) * Ss + kbase * 64 + gc * 8], &Vtg[0][row * 64]);
  }

  // Q as B-operand: B[n=q=lane&31][k=hi*8+j], 4 dk-steps of 16
  bf16x8 qf[4];
#pragma unroll
  for (int ks = 0; ks < 4; ks++)
    qf[ks] = *(const bf16x8*)&Q[head + (size_t)(q0 + m) * 64 + ks * 16 + hi * 8];

  const bf16_t oneb = f2b(1.0f);
  const bf16x8 ones = {oneb, oneb, oneb, oneb, oneb, oneb, oneb, oneb};

  f32x16 o0, o1, ol;
#pragma unroll
  for (int i = 0; i < 16; i++) { o0[i] = 0.f; o1[i] = 0.f; ol[i] = 0.f; }

  constexpr int NTg = 16;  // tiles per group
  for (int it = 0; it < NTg; it++) {
    const int cur = it & 1;
    __syncthreads();  // buf cur staged (vmcnt drain); buf cur^1 free

    int mv = maskb[it * 64 + lane];

    // prefetch next tile (overlaps with compute)
    if (it + 1 < NTg) {
      int nxt = cur ^ 1;
      int t = kbase + it + 1;
      for (int r = 0; r < 2; r++) {
        int row = r * 32 + wl * 8;
        gload_lds16(&K[head + (size_t)(t * 64 + row + sr) * 64 + gc * 8],
                    &Ksg[nxt][row * 64]);
        gload_lds16(&Vt[head + (size_t)(row + sr) * Ss + t * 64 + gc * 8],
                    &Vtg[nxt][row * 64]);
      }
    }

    // QK^T swapped: lane q=lane&31, keys = nt*32 + 8*(reg>>2) + 4*hi + (reg&3)
    f32x16 sc[2];
#pragma unroll
    for (int i = 0; i < 16; i++) { sc[0][i] = 0.f; sc[1][i] = 0.f; }

    __builtin_amdgcn_s_setprio(1);
#pragma unroll
    for (int ks = 0; ks < 4; ks++) {
      const int pc = ((ks * 2 + hi) ^ (m & 7)) * 8;
      bf16x8 k0 = *(const bf16x8*)&Ksg[cur][m * 64 + pc];
      bf16x8 k1 = *(const bf16x8*)&Ksg[cur][(32 + m) * 64 + pc];
      sc[0] = __builtin_amdgcn_mfma_f32_32x32x16_bf16(k0, qf[ks], sc[0], 0, 0, 0);
      sc[1] = __builtin_amdgcn_mfma_f32_32x32x16_bf16(k1, qf[ks], sc[1], 0, 0, 0);
    }
    __builtin_amdgcn_s_setprio(0);

    // softmax numerator: P = 2^(qk) (log2e folded into Q); ballot mask path
    unsigned long long bits = __ballot(mv != 0);
    if (bits == ~0ull) {
#pragma unroll
      for (int nt = 0; nt < 2; nt++)
#pragma unroll
        for (int i = 0; i < 16; i++) sc[nt][i] = exp2_fast(sc[nt][i]);
    } else {
#pragma unroll
      for (int nt = 0; nt < 2; nt++) {
        u32 wb = (u32)(bits >> (nt * 32));
        u32 wsh = hi ? (wb >> 4) : wb;  // key = 8g + 4*hi + r
#pragma unroll
        for (int i = 0; i < 16; i++) {
          int bitpos = 8 * (i >> 2) + (i & 3);
          sc[nt][i] = ((wsh >> bitpos) & 1u) ? exp2_fast(sc[nt][i]) : 0.f;
        }
      }
    }

    // PV: per k-step t build A-frag P[q=lane&31][k=t*16+hi*8+j] in-register.
    __builtin_amdgcn_s_setprio(1);
#pragma unroll
    for (int t = 0; t < 4; t++) {
      const int nt = t >> 1, gA = 2 * (t & 1), gB = gA + 1;
      u32 a0 = cvtpk(sc[nt][4 * gA + 0], sc[nt][4 * gA + 1]);
      u32 a1 = cvtpk(sc[nt][4 * gA + 2], sc[nt][4 * gA + 3]);
      u32 b0 = cvtpk(sc[nt][4 * gB + 0], sc[nt][4 * gB + 1]);
      u32 b1 = cvtpk(sc[nt][4 * gB + 2], sc[nt][4 * gB + 3]);
      swap32(a0, b0);
      swap32(a1, b1);
      int4 wv = {(int)a0, (int)a1, (int)b0, (int)b1};
      bf16x8 pa = __builtin_bit_cast(bf16x8, wv);

      ol = __builtin_amdgcn_mfma_f32_32x32x16_bf16(pa, ones, ol, 0, 0, 0);
      const int pc = ((t * 2 + hi) ^ (m & 7)) * 8;
      bf16x8 v0 = *(const bf16x8*)&Vtg[cur][m * 64 + pc];
      bf16x8 v1 = *(const bf16x8*)&Vtg[cur][(32 + m) * 64 + pc];
      o0 = __builtin_amdgcn_mfma_f32_32x32x16_bf16(pa, v0, o0, 0, 0, 0);
      o1 = __builtin_amdgcn_mfma_f32_32x32x16_bf16(pa, v1, o1, 0, 0, 0);
    }
    __builtin_amdgcn_s_setprio(0);
  }

  // ---- combine groups: o = oA + oB, l = lA + lB (exact; no max tracking) ----
  __syncthreads();  // all compute done; staging LDS reusable
  f32x4* cmb = (f32x4*)smem;  // 12 chunks x 256 lanes x 16B = 48KB
  if (g == 1) {
#pragma unroll
    for (int c = 0; c < 4; c++) {
      f32x4 t0 = {o0[4 * c], o0[4 * c + 1], o0[4 * c + 2], o0[4 * c + 3]};
      f32x4 t1 = {o1[4 * c], o1[4 * c + 1], o1[4 * c + 2], o1[4 * c + 3]};
      f32x4 t2 = {ol[4 * c], ol[4 * c + 1], ol[4 * c + 2], ol[4 * c + 3]};
      cmb[(c + 0) * 256 + wl * 64 + lane] = t0;
      cmb[(c + 4) * 256 + wl * 64 + lane] = t1;
      cmb[(c + 8) * 256 + wl * 64 + lane] = t2;
    }
  }
  __syncthreads();
  if (g == 0) {
#pragma unroll
    for (int c = 0; c < 4; c++) {
      f32x4 p0 = cmb[(c + 0) * 256 + wl * 64 + lane];
      f32x4 p1 = cmb[(c + 4) * 256 + wl * 64 + lane];
      f32x4 p2 = cmb[(c + 8) * 256 + wl * 64 + lane];
#pragma unroll
      for (int k = 0; k < 4; k++) {
        o0[4 * c + k] += p0[k];
        o1[4 * c + k] += p1[k];
        ol[4 * c + k] += p2[k];
      }
    }
    f32x16 inv;
#pragma unroll
    for (int r = 0; r < 16; r++) inv[r] = 1.0f / ol[r];
#pragma unroll
    for (int r = 0; r < 16; r++) {
      int s_ = q0 + (r & 3) + 8 * (r >> 2) + 4 * hi;
      size_t base = ((size_t)(b_ * Ss + s_)) * Dd + h_ * 64;
      ctx[base + m] = f2b(o0[r] * inv[r]);
      ctx[base + 32 + m] = f2b(o1[r] * inv[r]);
    }
  }
}

// ---------------------------------------------------------------------------
// Out-proj: out = ctx @ Wo^T + bo (fp32 out). 64x128 tiles, grid (8,64),
// XCD-bijective swizzle (512 = 8 x 64).
// ---------------------------------------------------------------------------
template <bool WB16>
__global__ __launch_bounds__(256) void gemm_out(
    const bf16_t* __restrict__ A, const float* __restrict__ Wf,
    const bf16_t* __restrict__ Wb, const float* __restrict__ bias,
    float* __restrict__ out) {
  __shared__ __align__(16) bf16_t As[64 * 32];
  __shared__ __align__(16) bf16_t Ws[128 * 32];

  const int fid = (int)(blockIdx.y * gridDim.x + blockIdx.x);
  const int swz = (fid & 7) * 64 + (fid >> 3);
  const int bx = swz & 7, by = swz >> 3;

  const int tid = threadIdx.x;
  const int lane = tid & 63, w = tid >> 6;
  const int quad = lane >> 4, c = lane & 15;
  const int wm = w >> 1, wn = w & 1;
  const int m0 = by * 64, n0 = bx * 128;
  const int trow = tid >> 1, tcol = (tid & 1) * 16;
  const int srow = lane >> 2, scol = (lane & 3) * 8;

  const f32x4 vzero = {0.f, 0.f, 0.f, 0.f};
  f32x4 acc[2][4];
  for (int i = 0; i < 2; i++)
    for (int j = 0; j < 4; j++) acc[i][j] = vzero;

  for (int k0 = 0; k0 < 1024; k0 += 32) {
    gload_lds16(&A[(size_t)(m0 + w * 16 + srow) * 1024 + k0 + scol], &As[(w * 16) * 32]);
    if (WB16) {
      for (int r = 0; r < 2; r++) {
        int row = r * 64 + w * 16;
        gload_lds16(&Wb[(size_t)(n0 + row + srow) * 1024 + k0 + scol], &Ws[row * 32]);
      }
    } else {
      cvt16_core(&Wf[(size_t)(n0 + trow) * 1024 + k0 + tcol], &Ws[trow * 32 + tcol]);
    }
    __syncthreads();

    bf16x8 af[2], bfr[4];
    for (int i = 0; i < 2; i++)
      af[i] = *(const bf16x8*)&As[(wm * 32 + i * 16 + c) * 32 + quad * 8];
    for (int j = 0; j < 4; j++)
      bfr[j] = *(const bf16x8*)&Ws[(wn * 64 + j * 16 + c) * 32 + quad * 8];
    for (int i = 0; i < 2; i++)
      for (int j = 0; j < 4; j++)
        acc[i][j] = __builtin_amdgcn_mfma_f32_16x16x32_bf16(af[i], bfr[j], acc[i][j], 0, 0, 0);
    __syncthreads();
  }

  for (int j = 0; j < 4; j++) {
    int n = n0 + wn * 64 + j * 16 + c;
    float bv = bias[n];
    for (int i = 0; i < 2; i++) {
      int mbase = m0 + wm * 32 + i * 16 + quad * 4;
      for (int r = 0; r < 4; r++)
        out[(size_t)(mbase + r) * 1024 + n] = acc[i][j][r] + bv;
    }
  }
}

// ---------------------------------------------------------------------------
extern "C" void kernel_launch(void* const* d_in, const int* in_sizes, int n_in,
                              void* d_out, int out_size, void* d_ws, size_t ws_size,
                              hipStream_t stream) {
  const float* x  = (const float*)d_in[0];
  const int* mask = (const int*)d_in[1];
  const float* Wq = (const float*)d_in[2];
  const float* bq = (const float*)d_in[3];
  const float* Wk = (const float*)d_in[4];
  const float* bk = (const float*)d_in[5];
  const float* Wv = (const float*)d_in[6];
  const float* bv = (const float*)d_in[7];
  const float* Wo = (const float*)d_in[8];
  const float* bo = (const float*)d_in[9];
  float* out = (float*)d_out;

  bf16_t* ws = (bf16_t*)d_ws;
  const size_t QKV_ELEMS = (size_t)2 * Hh * Ss * DKk;  // 4M
  bf16_t* xb  = ws;          // reused as ctx after gemm_qkv is done with it
  bf16_t* Qb  = ws + QKV_ELEMS;
  bf16_t* Kb  = ws + 2 * QKV_ELEMS;
  bf16_t* Vt  = ws + 3 * QKV_ELEMS;
  bf16_t* Wb  = ws + 4 * QKV_ELEMS;  // 4M elems (4 matrices x 1M)
  bf16_t* ctx = xb;

  const bool wb16 = ws_size >= (size_t)40 * 1024 * 1024;

  if (wb16) {
    cvt_all<<<dim3(2048), 256, 0, stream>>>(x, Wq, Wk, Wv, Wo, xb, Wb);
    gemm_qkv<true><<<dim3(8, 32, 3), 256, 0, stream>>>(
        xb, Wq, Wk, Wv, Wb, bq, bk, bv, Qb, Kb, Vt);
  } else {
    cvt16<<<dim3(1024), 256, 0, stream>>>(x, xb);
    gemm_qkv<false><<<dim3(8, 32, 3), 256, 0, stream>>>(
        xb, Wq, Wk, Wv, ws /*unused*/, bq, bk, bv, Qb, Kb, Vt);
  }
  attn_fwd<<<dim3(Ss / 128, 2 * Hh), 512, 0, stream>>>(Qb, Kb, Vt, mask, ctx);
  if (wb16)
    gemm_out<true><<<dim3(8, 64), 256, 0, stream>>>(ctx, Wo, Wb + 3 * (1u << 20), bo, out);
  else
    gemm_out<false><<<dim3(8, 64), 256, 0, stream>>>(ctx, Wo, ws /*unused*/, bo, out);
}

// Round 3
// 187.089 us; speedup vs baseline: 1.1616x; 1.1616x over previous
//
#include <hip/hip_runtime.h>
#include <hip/hip_bf16.h>

// MultiHeadSelfAttention: B=2 S=2048 D=1024 H=16 DK=64. fp32 I/O, bf16 internals.
// [cvt x+W fused] -> [QKV gemm (Q pre-scaled by 0.125*log2e, V transposed)] ->
// [flash attn v3b: swapped QK^T (mfma(K,Q), 32x32x16), in-register softmax via
//  v_exp_f32 + cvt_pk_bf16 + permlane32_swap; KEY-SPLIT 8-wave blocks (group 0:
//  tiles 0-15, group 1: tiles 16-31; exact combine o=oA+oB,l=lA+lB via LDS);
//  double-buffered K/V per group; XCD-bijective swizzle.
//  NOTE: plain __launch_bounds__(512) — round-2's (512,4) pinned VGPR to 64
//  and spilled accumulators to scratch (+64MB HBM traffic, 82us). Natural
//  alloc ~112 VGPR still gives 2 blocks/CU (16 waves) without spills.]
// -> [out-proj 64x128 tiles].
// ws (bf16 elems): xb/ctx[0], Q[4M], K[8M], Vt[12M], Wb[16M..20M] => 40 MB.

#define DEV __device__ __forceinline__

typedef __bf16 bf16_t;
typedef __bf16 bf16x4 __attribute__((ext_vector_type(4)));
typedef __bf16 bf16x8 __attribute__((ext_vector_type(8)));
typedef float f32x4 __attribute__((ext_vector_type(4)));
typedef float f32x16 __attribute__((ext_vector_type(16)));
typedef unsigned int u32;

constexpr int Ss = 2048, Dd = 1024, Hh = 16, DKk = 64;

DEV void gload_lds16(const void* g, void* l) {
  __builtin_amdgcn_global_load_lds(
      (__attribute__((address_space(1))) void*)(g),
      (__attribute__((address_space(3))) void*)(l), 16, 0, 0);
}

DEV bf16_t f2b(float v) { return (bf16_t)v; }

DEV u32 cvtpk(float lo, float hi) {
  u32 r;
  asm("v_cvt_pk_bf16_f32 %0, %1, %2" : "=v"(r) : "v"(lo), "v"(hi));
  return r;
}

// new a0[l+32] = old b0[l]; new b0[l] = old a0[l+32] (lanes l<32).
DEV void swap32(u32& a, u32& b) {
  asm("v_permlane32_swap_b32 %0, %1" : "+v"(a), "+v"(b));
}

DEV float exp2_fast(float x) {  // 2^x, single v_exp_f32
  float r;
  asm("v_exp_f32 %0, %1" : "=v"(r) : "v"(x));
  return r;
}

// 16 fp32 -> bf16 (32B out)
DEV void cvt16_core(const float* src, bf16_t* dst) {
  const float4* s4 = (const float4*)src;
  float4 a = s4[0], b = s4[1], c = s4[2], d = s4[3];
  bf16x8 lo = {f2b(a.x), f2b(a.y), f2b(a.z), f2b(a.w), f2b(b.x), f2b(b.y), f2b(b.z), f2b(b.w)};
  bf16x8 hi = {f2b(c.x), f2b(c.y), f2b(c.z), f2b(c.w), f2b(d.x), f2b(d.y), f2b(d.z), f2b(d.w)};
  *(bf16x8*)dst = lo;
  *(bf16x8*)(dst + 8) = hi;
}

__global__ __launch_bounds__(256) void cvt16(const float* __restrict__ x,
                                             bf16_t* __restrict__ xb) {
  size_t i = ((size_t)blockIdx.x * 256 + threadIdx.x) * 16;
  cvt16_core(x + i, xb + i);
}

// fused: x (4M) -> xb; Wq/Wk/Wv/Wo (1M each) -> Wb. grid 2048x256.
__global__ __launch_bounds__(256) void cvt_all(
    const float* __restrict__ x,
    const float* __restrict__ wq, const float* __restrict__ wk,
    const float* __restrict__ wv, const float* __restrict__ wo,
    bf16_t* __restrict__ xb, bf16_t* __restrict__ Wb) {
  size_t i = ((size_t)blockIdx.x * 256 + threadIdx.x) * 16;
  const size_t XN = (size_t)4 << 20;
  if (i < XN) {
    cvt16_core(x + i, xb + i);
  } else {
    size_t j = i - XN;
    int z = (int)(j >> 20);
    size_t o = j & (((size_t)1 << 20) - 1);
    const float* s = (z == 0) ? wq : ((z == 1) ? wk : ((z == 2) ? wv : wo));
    cvt16_core(s + o, Wb + j);
  }
}

// ---------------------------------------------------------------------------
// QKV GEMM: C = xb @ W^T + b. z=0 Q [B*H,S,DK] (pre-scaled by 0.125*log2e);
// z=1 K [B*H,S,DK]; z=2 Vt [B*H,DK,S] (packed 8B stores).
// XCD-bijective block swizzle over 768 = 8 x 96 workgroups.
// ---------------------------------------------------------------------------
template <bool WB16>
__global__ __launch_bounds__(256) void gemm_qkv(
    const bf16_t* __restrict__ A,
    const float* __restrict__ W0, const float* __restrict__ W1, const float* __restrict__ W2,
    const bf16_t* __restrict__ Wb,
    const float* __restrict__ b0, const float* __restrict__ b1, const float* __restrict__ b2,
    bf16_t* __restrict__ o0, bf16_t* __restrict__ o1, bf16_t* __restrict__ o2) {
  // swizzle: fid -> xcd-contiguous chunks (768 % 8 == 0, bijective)
  const int fid = (int)((blockIdx.z * gridDim.y + blockIdx.y) * gridDim.x + blockIdx.x);
  const int swz = (fid & 7) * 96 + (fid >> 3);
  const int bx = swz & 7, by = (swz >> 3) & 31, z = swz >> 8;

  const float* Wf = (z == 0) ? W0 : ((z == 1) ? W1 : W2);
  const bf16_t* Wbf = Wb + (size_t)z * (1u << 20);
  const float* bias = (z == 0) ? b0 : ((z == 1) ? b1 : b2);
  bf16_t* out = (z == 0) ? o0 : ((z == 1) ? o1 : o2);
  const float scl = (z == 0) ? 0.18033688f : 1.0f;  // 0.125 * log2(e)

  __shared__ __align__(16) bf16_t As[128 * 32];
  __shared__ __align__(16) bf16_t Ws[128 * 32];

  const int tid = threadIdx.x;
  const int lane = tid & 63, w = tid >> 6;
  const int quad = lane >> 4, c = lane & 15;
  const int wm = w >> 1, wn = w & 1;
  const int m0 = by * 128, n0 = bx * 128;
  const int trow = tid >> 1, tcol = (tid & 1) * 16;
  const int srow = lane >> 2, scol = (lane & 3) * 8;

  const f32x4 vzero = {0.f, 0.f, 0.f, 0.f};
  f32x4 acc[4][4];
  for (int i = 0; i < 4; i++)
    for (int j = 0; j < 4; j++) acc[i][j] = vzero;

  for (int k0 = 0; k0 < 1024; k0 += 32) {
    for (int r = 0; r < 2; r++) {
      int row = r * 64 + w * 16;  // wave-uniform LDS base
      gload_lds16(&A[(size_t)(m0 + row + srow) * 1024 + k0 + scol], &As[row * 32]);
      if (WB16)
        gload_lds16(&Wbf[(size_t)(n0 + row + srow) * 1024 + k0 + scol], &Ws[row * 32]);
    }
    if (!WB16)
      cvt16_core(&Wf[(size_t)(n0 + trow) * 1024 + k0 + tcol], &Ws[trow * 32 + tcol]);
    __syncthreads();

    bf16x8 af[4], bfr[4];
    for (int i = 0; i < 4; i++)
      af[i] = *(const bf16x8*)&As[(wm * 64 + i * 16 + c) * 32 + quad * 8];
    for (int j = 0; j < 4; j++)
      bfr[j] = *(const bf16x8*)&Ws[(wn * 64 + j * 16 + c) * 32 + quad * 8];
    for (int i = 0; i < 4; i++)
      for (int j = 0; j < 4; j++)
        acc[i][j] = __builtin_amdgcn_mfma_f32_16x16x32_bf16(af[i], bfr[j], acc[i][j], 0, 0, 0);
    __syncthreads();
  }

  for (int j = 0; j < 4; j++) {
    int n = n0 + wn * 64 + j * 16 + c;
    float bv = bias[n];
    for (int i = 0; i < 4; i++) {
      int mbase = m0 + wm * 64 + i * 16 + quad * 4;
      int b_ = mbase >> 11, s_ = mbase & 2047;
      int h_ = n >> 6, dk_ = n & 63;
      if (z < 2) {
        for (int r = 0; r < 4; r++)
          out[((size_t)(b_ * Hh + h_) * Ss + (s_ + r)) * DKk + dk_] =
              f2b((acc[i][j][r] + bv) * scl);
      } else {
        bf16x4 pk;
        for (int r = 0; r < 4; r++) pk[r] = f2b(acc[i][j][r] + bv);
        *(bf16x4*)&out[((size_t)(b_ * Hh + h_) * DKk + dk_) * Ss + s_] = pk;
      }
    }
  }
}

// ---------------------------------------------------------------------------
// Flash attention v3b: swapped QK^T, in-register softmax, KEY-SPLIT 8 waves.
// Grid 512 blocks x 512 threads. Waves 0-3 (group 0): key tiles 0..15;
// waves 4-7 (group 1): tiles 16..31. Each group double-buffers its own
// 64x64 K/V LDS tiles. Exact combine (no online max): o=oA+oB, l=lA+lB
// via 48KB LDS scratch (reuses staging buffers after last barrier).
// mfma_f32_32x32x16_bf16: A[m=lane&31][k=(lane>>5)*8+j]; C col=lane&31,
// row=(reg&3)+8*(reg>>2)+4*(lane>>5).
// Plain launch_bounds(512): natural ~112 VGPR -> 2 blocks/CU, no spill.
// ---------------------------------------------------------------------------
__global__ __launch_bounds__(512) void attn_fwd(
    const bf16_t* __restrict__ Q, const bf16_t* __restrict__ K,
    const bf16_t* __restrict__ Vt, const int* __restrict__ mask,
    bf16_t* __restrict__ ctx) {
  __shared__ __align__(16) bf16_t smem[2][2][2][64 * 64];  // [K/V][grp][buf] 64KB

  const int tid = threadIdx.x, lane = tid & 63, w = tid >> 6;
  const int g = w >> 2, wl = w & 3;
  const int m = lane & 31, hi = lane >> 5;

  // XCD-bijective swizzle: 512 wgs = 8 xcds x 64; each XCD owns 4 whole heads.
  const int fid = (int)(blockIdx.y * gridDim.x + blockIdx.x);
  const int xcd = fid & 7, j_ = fid >> 3;
  const int bh = xcd * 4 + (j_ >> 4);
  const int qblk = j_ & 15;

  const int b_ = bh >> 4, h_ = bh & 15;
  const int q0 = qblk * 128 + wl * 32;
  const size_t head = (size_t)bh * Ss * DKk;
  const int* maskb = mask + b_ * Ss + g * 1024;
  const int kbase = g * 16;  // this group's first key tile

  bf16_t (*Ksg)[64 * 64] = smem[0][g];
  bf16_t (*Vtg)[64 * 64] = smem[1][g];

  const int sr = lane >> 3;        // staging row within 8
  const int gc = (lane & 7) ^ sr;  // swizzled source chunk

  // prefetch this group's tile 0 into buf 0
  for (int r = 0; r < 2; r++) {
    int row = r * 32 + wl * 8;  // wave-uniform
    gload_lds16(&K[head + (size_t)(kbase * 64 + row + sr) * 64 + gc * 8], &Ksg[0][row * 64]);
    gload_lds16(&Vt[head + (size_t)(row + sr) * Ss + kbase * 64 + gc * 8], &Vtg[0][row * 64]);
  }

  // Q as B-operand: B[n=q=lane&31][k=hi*8+j], 4 dk-steps of 16
  bf16x8 qf[4];
#pragma unroll
  for (int ks = 0; ks < 4; ks++)
    qf[ks] = *(const bf16x8*)&Q[head + (size_t)(q0 + m) * 64 + ks * 16 + hi * 8];

  const bf16_t oneb = f2b(1.0f);
  const bf16x8 ones = {oneb, oneb, oneb, oneb, oneb, oneb, oneb, oneb};

  f32x16 o0, o1, ol;
#pragma unroll
  for (int i = 0; i < 16; i++) { o0[i] = 0.f; o1[i] = 0.f; ol[i] = 0.f; }

  constexpr int NTg = 16;  // tiles per group
  for (int it = 0; it < NTg; it++) {
    const int cur = it & 1;
    __syncthreads();  // buf cur staged (vmcnt drain); buf cur^1 free

    int mv = maskb[it * 64 + lane];

    // prefetch next tile (overlaps with compute)
    if (it + 1 < NTg) {
      int nxt = cur ^ 1;
      int t = kbase + it + 1;
      for (int r = 0; r < 2; r++) {
        int row = r * 32 + wl * 8;
        gload_lds16(&K[head + (size_t)(t * 64 + row + sr) * 64 + gc * 8],
                    &Ksg[nxt][row * 64]);
        gload_lds16(&Vt[head + (size_t)(row + sr) * Ss + t * 64 + gc * 8],
                    &Vtg[nxt][row * 64]);
      }
    }

    // QK^T swapped: lane q=lane&31, keys = nt*32 + 8*(reg>>2) + 4*hi + (reg&3)
    f32x16 sc[2];
#pragma unroll
    for (int i = 0; i < 16; i++) { sc[0][i] = 0.f; sc[1][i] = 0.f; }

    __builtin_amdgcn_s_setprio(1);
#pragma unroll
    for (int ks = 0; ks < 4; ks++) {
      const int pc = ((ks * 2 + hi) ^ (m & 7)) * 8;
      bf16x8 k0 = *(const bf16x8*)&Ksg[cur][m * 64 + pc];
      bf16x8 k1 = *(const bf16x8*)&Ksg[cur][(32 + m) * 64 + pc];
      sc[0] = __builtin_amdgcn_mfma_f32_32x32x16_bf16(k0, qf[ks], sc[0], 0, 0, 0);
      sc[1] = __builtin_amdgcn_mfma_f32_32x32x16_bf16(k1, qf[ks], sc[1], 0, 0, 0);
    }
    __builtin_amdgcn_s_setprio(0);

    // softmax numerator: P = 2^(qk) (log2e folded into Q); ballot mask path
    unsigned long long bits = __ballot(mv != 0);
    if (bits == ~0ull) {
#pragma unroll
      for (int nt = 0; nt < 2; nt++)
#pragma unroll
        for (int i = 0; i < 16; i++) sc[nt][i] = exp2_fast(sc[nt][i]);
    } else {
#pragma unroll
      for (int nt = 0; nt < 2; nt++) {
        u32 wb = (u32)(bits >> (nt * 32));
        u32 wsh = hi ? (wb >> 4) : wb;  // key = 8g + 4*hi + r
#pragma unroll
        for (int i = 0; i < 16; i++) {
          int bitpos = 8 * (i >> 2) + (i & 3);
          sc[nt][i] = ((wsh >> bitpos) & 1u) ? exp2_fast(sc[nt][i]) : 0.f;
        }
      }
    }

    // PV: per k-step t build A-frag P[q=lane&31][k=t*16+hi*8+j] in-register.
    __builtin_amdgcn_s_setprio(1);
#pragma unroll
    for (int t = 0; t < 4; t++) {
      const int nt = t >> 1, gA = 2 * (t & 1), gB = gA + 1;
      u32 a0 = cvtpk(sc[nt][4 * gA + 0], sc[nt][4 * gA + 1]);
      u32 a1 = cvtpk(sc[nt][4 * gA + 2], sc[nt][4 * gA + 3]);
      u32 b0 = cvtpk(sc[nt][4 * gB + 0], sc[nt][4 * gB + 1]);
      u32 b1 = cvtpk(sc[nt][4 * gB + 2], sc[nt][4 * gB + 3]);
      swap32(a0, b0);
      swap32(a1, b1);
      int4 wv = {(int)a0, (int)a1, (int)b0, (int)b1};
      bf16x8 pa = __builtin_bit_cast(bf16x8, wv);

      ol = __builtin_amdgcn_mfma_f32_32x32x16_bf16(pa, ones, ol, 0, 0, 0);
      const int pc = ((t * 2 + hi) ^ (m & 7)) * 8;
      bf16x8 v0 = *(const bf16x8*)&Vtg[cur][m * 64 + pc];
      bf16x8 v1 = *(const bf16x8*)&Vtg[cur][(32 + m) * 64 + pc];
      o0 = __builtin_amdgcn_mfma_f32_32x32x16_bf16(pa, v0, o0, 0, 0, 0);
      o1 = __builtin_amdgcn_mfma_f32_32x32x16_bf16(pa, v1, o1, 0, 0, 0);
    }
    __builtin_amdgcn_s_setprio(0);
  }

  // ---- combine groups: o = oA + oB, l = lA + lB (exact; no max tracking) ----
  __syncthreads();  // all compute done; staging LDS reusable
  f32x4* cmb = (f32x4*)smem;  // 12 chunks x 256 lanes x 16B = 48KB
  if (g == 1) {
#pragma unroll
    for (int c = 0; c < 4; c++) {
      f32x4 t0 = {o0[4 * c], o0[4 * c + 1], o0[4 * c + 2], o0[4 * c + 3]};
      f32x4 t1 = {o1[4 * c], o1[4 * c + 1], o1[4 * c + 2], o1[4 * c + 3]};
      f32x4 t2 = {ol[4 * c], ol[4 * c + 1], ol[4 * c + 2], ol[4 * c + 3]};
      cmb[(c + 0) * 256 + wl * 64 + lane] = t0;
      cmb[(c + 4) * 256 + wl * 64 + lane] = t1;
      cmb[(c + 8) * 256 + wl * 64 + lane] = t2;
    }
  }
  __syncthreads();
  if (g == 0) {
#pragma unroll
    for (int c = 0; c < 4; c++) {
      f32x4 p0 = cmb[(c + 0) * 256 + wl * 64 + lane];
      f32x4 p1 = cmb[(c + 4) * 256 + wl * 64 + lane];
      f32x4 p2 = cmb[(c + 8) * 256 + wl * 64 + lane];
#pragma unroll
      for (int k = 0; k < 4; k++) {
        o0[4 * c + k] += p0[k];
        o1[4 * c + k] += p1[k];
        ol[4 * c + k] += p2[k];
      }
    }
    f32x16 inv;
#pragma unroll
    for (int r = 0; r < 16; r++) inv[r] = 1.0f / ol[r];
#pragma unroll
    for (int r = 0; r < 16; r++) {
      int s_ = q0 + (r & 3) + 8 * (r >> 2) + 4 * hi;
      size_t base = ((size_t)(b_ * Ss + s_)) * Dd + h_ * 64;
      ctx[base + m] = f2b(o0[r] * inv[r]);
      ctx[base + 32 + m] = f2b(o1[r] * inv[r]);
    }
  }
}

// ---------------------------------------------------------------------------
// Out-proj: out = ctx @ Wo^T + bo (fp32 out). 64x128 tiles, grid (8,64),
// XCD-bijective swizzle (512 = 8 x 64).
// ---------------------------------------------------------------------------
template <bool WB16>
__global__ __launch_bounds__(256) void gemm_out(
    const bf16_t* __restrict__ A, const float* __restrict__ Wf,
    const bf16_t* __restrict__ Wb, const float* __restrict__ bias,
    float* __restrict__ out) {
  __shared__ __align__(16) bf16_t As[64 * 32];
  __shared__ __align__(16) bf16_t Ws[128 * 32];

  const int fid = (int)(blockIdx.y * gridDim.x + blockIdx.x);
  const int swz = (fid & 7) * 64 + (fid >> 3);
  const int bx = swz & 7, by = swz >> 3;

  const int tid = threadIdx.x;
  const int lane = tid & 63, w = tid >> 6;
  const int quad = lane >> 4, c = lane & 15;
  const int wm = w >> 1, wn = w & 1;
  const int m0 = by * 64, n0 = bx * 128;
  const int trow = tid >> 1, tcol = (tid & 1) * 16;
  const int srow = lane >> 2, scol = (lane & 3) * 8;

  const f32x4 vzero = {0.f, 0.f, 0.f, 0.f};
  f32x4 acc[2][4];
  for (int i = 0; i < 2; i++)
    for (int j = 0; j < 4; j++) acc[i][j] = vzero;

  for (int k0 = 0; k0 < 1024; k0 += 32) {
    gload_lds16(&A[(size_t)(m0 + w * 16 + srow) * 1024 + k0 + scol], &As[(w * 16) * 32]);
    if (WB16) {
      for (int r = 0; r < 2; r++) {
        int row = r * 64 + w * 16;
        gload_lds16(&Wb[(size_t)(n0 + row + srow) * 1024 + k0 + scol], &Ws[row * 32]);
      }
    } else {
      cvt16_core(&Wf[(size_t)(n0 + trow) * 1024 + k0 + tcol], &Ws[trow * 32 + tcol]);
    }
    __syncthreads();

    bf16x8 af[2], bfr[4];
    for (int i = 0; i < 2; i++)
      af[i] = *(const bf16x8*)&As[(wm * 32 + i * 16 + c) * 32 + quad * 8];
    for (int j = 0; j < 4; j++)
      bfr[j] = *(const bf16x8*)&Ws[(wn * 64 + j * 16 + c) * 32 + quad * 8];
    for (int i = 0; i < 2; i++)
      for (int j = 0; j < 4; j++)
        acc[i][j] = __builtin_amdgcn_mfma_f32_16x16x32_bf16(af[i], bfr[j], acc[i][j], 0, 0, 0);
    __syncthreads();
  }

  for (int j = 0; j < 4; j++) {
    int n = n0 + wn * 64 + j * 16 + c;
    float bv = bias[n];
    for (int i = 0; i < 2; i++) {
      int mbase = m0 + wm * 32 + i * 16 + quad * 4;
      for (int r = 0; r < 4; r++)
        out[(size_t)(mbase + r) * 1024 + n] = acc[i][j][r] + bv;
    }
  }
}

// ---------------------------------------------------------------------------
extern "C" void kernel_launch(void* const* d_in, const int* in_sizes, int n_in,
                              void* d_out, int out_size, void* d_ws, size_t ws_size,
                              hipStream_t stream) {
  const float* x  = (const float*)d_in[0];
  const int* mask = (const int*)d_in[1];
  const float* Wq = (const float*)d_in[2];
  const float* bq = (const float*)d_in[3];
  const float* Wk = (const float*)d_in[4];
  const float* bk = (const float*)d_in[5];
  const float* Wv = (const float*)d_in[6];
  const float* bv = (const float*)d_in[7];
  const float* Wo = (const float*)d_in[8];
  const float* bo = (const float*)d_in[9];
  float* out = (float*)d_out;

  bf16_t* ws = (bf16_t*)d_ws;
  const size_t QKV_ELEMS = (size_t)2 * Hh * Ss * DKk;  // 4M
  bf16_t* xb  = ws;          // reused as ctx after gemm_qkv is done with it
  bf16_t* Qb  = ws + QKV_ELEMS;
  bf16_t* Kb  = ws + 2 * QKV_ELEMS;
  bf16_t* Vt  = ws + 3 * QKV_ELEMS;
  bf16_t* Wb  = ws + 4 * QKV_ELEMS;  // 4M elems (4 matrices x 1M)
  bf16_t* ctx = xb;

  const bool wb16 = ws_size >= (size_t)40 * 1024 * 1024;

  if (wb16) {
    cvt_all<<<dim3(2048), 256, 0, stream>>>(x, Wq, Wk, Wv, Wo, xb, Wb);
    gemm_qkv<true><<<dim3(8, 32, 3), 256, 0, stream>>>(
        xb, Wq, Wk, Wv, Wb, bq, bk, bv, Qb, Kb, Vt);
  } else {
    cvt16<<<dim3(1024), 256, 0, stream>>>(x, xb);
    gemm_qkv<false><<<dim3(8, 32, 3), 256, 0, stream>>>(
        xb, Wq, Wk, Wv, ws /*unused*/, bq, bk, bv, Qb, Kb, Vt);
  }
  attn_fwd<<<dim3(Ss / 128, 2 * Hh), 512, 0, stream>>>(Qb, Kb, Vt, mask, ctx);
  if (wb16)
    gemm_out<true><<<dim3(8, 64), 256, 0, stream>>>(ctx, Wo, Wb + 3 * (1u << 20), bo, out);
  else
    gemm_out<false><<<dim3(8, 64), 256, 0, stream>>>(ctx, Wo, ws /*unused*/, bo, out);
}